// Round 4
// baseline (279.989 us; speedup 1.0000x reference)
//
#include <hip/hip_runtime.h>
#include <math.h>

// Problem: bs=8, seq=2048, d_in=d_out=2048, R=8, ctr_out=32, ctr_final=4
// ws layout (floats): A[8*8*2048] | B[8*8*2048] | xa[8*2048*8]
// (B has SCALING folded in)

#define BS 8
#define SEQ 2048
#define DIM 2048
#define RR 8
#define SCALING 2.0f   // 16.0 / R

typedef float vf4 __attribute__((ext_vector_type(4)));

// ---------------------------------------------------------------------------
// Kernel 1: gating MLP + A/B generation. (unchanged — ~6 µs, off critical path)
// ---------------------------------------------------------------------------
__global__ void gate_ab_kernel(const float* __restrict__ ctr,
                               const float* __restrict__ gamma,
                               const float* __restrict__ beta,
                               const float* __restrict__ W1,
                               const float* __restrict__ b1,
                               const float* __restrict__ W2,
                               const float* __restrict__ b2,
                               const float* __restrict__ Wa,
                               const float* __restrict__ Wb,
                               float* __restrict__ A,
                               float* __restrict__ B) {
    __shared__ float z_s[BS][32];
    __shared__ float h_s[BS][60];
    __shared__ float logit_s[BS][4];
    __shared__ float gate_s[BS][4];
    const int tid = threadIdx.x;

    {
        const int b = tid >> 5, i = tid & 31;
        float v = ctr[b * 32 + i];
        float s = v;
        #pragma unroll
        for (int m = 16; m; m >>= 1) s += __shfl_xor(s, m, 64);
        const float mu = s * (1.0f / 32.0f);
        const float d = v - mu;
        float sq = d * d;
        #pragma unroll
        for (int m = 16; m; m >>= 1) sq += __shfl_xor(sq, m, 64);
        const float var = sq * (1.0f / 32.0f);
        z_s[b][i] = d * rsqrtf(var + 1e-5f) * gamma[i] + beta[i];
    }
    __syncthreads();

    for (int idx = tid; idx < BS * 60; idx += 256) {
        const int b = idx / 60, j = idx % 60;
        float acc = b1[j];
        #pragma unroll
        for (int k = 0; k < 32; ++k) acc += z_s[b][k] * W1[j * 32 + k];
        h_s[b][j] = fmaxf(acc, 0.0f);
    }
    __syncthreads();

    if (tid < 32) {
        const int b = tid >> 2, c = tid & 3;
        float acc = b2[c];
        for (int k = 0; k < 60; ++k) acc += h_s[b][k] * W2[c * 60 + k];
        logit_s[b][c] = acc;
    }
    __syncthreads();

    if (tid < 8) {
        float m = logit_s[tid][0];
        #pragma unroll
        for (int c = 1; c < 4; ++c) m = fmaxf(m, logit_s[tid][c]);
        float e[4], s = 0.0f;
        #pragma unroll
        for (int c = 0; c < 4; ++c) { e[c] = expf(logit_s[tid][c] - m); s += e[c]; }
        const float inv = 1.0f / s;
        #pragma unroll
        for (int c = 0; c < 4; ++c) gate_s[tid][c] = e[c] * inv;
    }
    __syncthreads();

    const vf4* __restrict__ Wa4 = (const vf4*)Wa;
    const vf4* __restrict__ Wb4 = (const vf4*)Wb;
    const int total = BS * RR * DIM;   // 131072
    for (int idx = blockIdx.x * 256 + tid; idx < total; idx += gridDim.x * 256) {
        const int b = idx >> 14, rd = idx & 16383;
        const vf4 g = *(const vf4*)gate_s[b];
        const vf4 wa = Wa4[rd];
        A[idx] = g.x * wa.x + g.y * wa.y + g.z * wa.z + g.w * wa.w;
        const vf4 wb = Wb4[rd];
        B[idx] = SCALING * (g.x * wb.x + g.y * wb.y + g.z * wb.z + g.w * wb.w);
    }
}

// ---------------------------------------------------------------------------
// Kernel 2: xa = x . A^T — pure READ stream, latency-hiding via TLP.
// 2 rows/wave -> 2048 blocks (8 blocks/CU, up to 24+ waves/CU resident).
// A[b] read from L2 (re-read per wave: 256 MB aggregate L2 traffic = ~8 us
// at L2 BW, negligible). No LDS, no barriers.
// ---------------------------------------------------------------------------
__global__ void __launch_bounds__(256, 6)
xa_kernel(const float* __restrict__ x, const float* __restrict__ A,
          float* __restrict__ xa) {
    const int b    = blockIdx.x >> 8;     // 256 blocks per sample
    const int tile = blockIdx.x & 255;    // 8 rows per block
    const int wave = threadIdx.x >> 6, lane = threadIdx.x & 63;
    const int row0 = tile * 8 + wave * 2;

    const float* __restrict__ xr = x + ((size_t)(b * SEQ + row0)) * DIM;
    const float* __restrict__ Ab = A + b * (RR * DIM);

    float acc[2][8];
    #pragma unroll
    for (int i = 0; i < 2; ++i)
        #pragma unroll
        for (int r = 0; r < 8; ++r) acc[i][r] = 0.0f;

    // fully-unrolled j-loop: compiler overlaps the 10 loads of each chunk
    // across iterations; 8 blocks/CU of TLP hides x (HBM/L3) latency.
    #pragma unroll
    for (int j = 0; j < 8; ++j) {
        const int d = j * 256 + lane * 4;
        vf4 xv0 = *(const vf4*)&xr[d];
        vf4 xv1 = *(const vf4*)&xr[DIM + d];
        vf4 a4[8];
        #pragma unroll
        for (int r = 0; r < 8; ++r) a4[r] = *(const vf4*)&Ab[r * DIM + d];
        #pragma unroll
        for (int r = 0; r < 8; ++r) {
            acc[0][r] += xv0.x * a4[r].x + xv0.y * a4[r].y +
                         xv0.z * a4[r].z + xv0.w * a4[r].w;
            acc[1][r] += xv1.x * a4[r].x + xv1.y * a4[r].y +
                         xv1.z * a4[r].z + xv1.w * a4[r].w;
        }
    }

    // butterfly reduce across 64 lanes -> every lane holds all 16 sums
    float xv[2][8];
    #pragma unroll
    for (int i = 0; i < 2; ++i) {
        #pragma unroll
        for (int r = 0; r < 8; ++r) {
            float v = acc[i][r];
            #pragma unroll
            for (int off = 32; off; off >>= 1) v += __shfl_xor(v, off, 64);
            xv[i][r] = v;
        }
    }

    // lanes 0..15 write xa: lane = i*8 + r (static cndmask selection)
    if (lane < 16) {
        float v = 0.0f;
        #pragma unroll
        for (int i = 0; i < 2; ++i)
            #pragma unroll
            for (int r = 0; r < 8; ++r)
                if (lane == i * 8 + r) v = xv[i][r];
        xa[((size_t)(b * SEQ + row0)) * RR + lane] = v;
    }
}

// ---------------------------------------------------------------------------
// Kernel 3: out = xa . B — pure WRITE stream, fill-like.
// Each wave owns a fixed 512-float column slice; its B[r][slice] lives in
// 16 vf4 REGISTERS (loaded once). Row loop: 2 uniform xa loads + 64 FMA +
// 2 KB of stores — no per-iteration L2 operand dependency on the store path.
// Plain float4 stores (NT vector stores scalarize -> 4x write amp, round 1).
// ---------------------------------------------------------------------------
__global__ void __launch_bounds__(256, 4)
out_kernel(const float* __restrict__ xa, const float* __restrict__ B,
           float* __restrict__ out) {
    const int b    = blockIdx.x >> 7;     // 128 blocks per sample
    const int tile = blockIdx.x & 127;    // 16 rows per block
    const int wave = threadIdx.x >> 6, lane = threadIdx.x & 63;
    const int row0 = tile * 16;
    const int col0 = wave * 512 + lane * 4;

    const float* __restrict__ Bb = B + b * (RR * DIM);

    // B slice -> registers, once per wave
    vf4 b0[8], b1[8];
    #pragma unroll
    for (int r = 0; r < 8; ++r) {
        b0[r] = *(const vf4*)&Bb[r * DIM + col0];
        b1[r] = *(const vf4*)&Bb[r * DIM + col0 + 256];
    }

    const float* __restrict__ xab = xa + ((size_t)(b * SEQ + row0)) * RR;
    float* __restrict__ ob = out + ((size_t)(b * SEQ + row0)) * DIM + col0;

    #pragma unroll 2
    for (int i = 0; i < 16; ++i) {
        const vf4 xlo = *(const vf4*)&xab[i * RR];
        const vf4 xhi = *(const vf4*)&xab[i * RR + 4];
        vf4 o0 = {0.0f, 0.0f, 0.0f, 0.0f};
        vf4 o1 = {0.0f, 0.0f, 0.0f, 0.0f};
        #pragma unroll
        for (int r = 0; r < 4; ++r) {
            const float f = xlo[r];
            o0.x += f * b0[r].x; o0.y += f * b0[r].y;
            o0.z += f * b0[r].z; o0.w += f * b0[r].w;
            o1.x += f * b1[r].x; o1.y += f * b1[r].y;
            o1.z += f * b1[r].z; o1.w += f * b1[r].w;
        }
        #pragma unroll
        for (int r = 0; r < 4; ++r) {
            const float f = xhi[r];
            o0.x += f * b0[r + 4].x; o0.y += f * b0[r + 4].y;
            o0.z += f * b0[r + 4].z; o0.w += f * b0[r + 4].w;
            o1.x += f * b1[r + 4].x; o1.y += f * b1[r + 4].y;
            o1.z += f * b1[r + 4].z; o1.w += f * b1[r + 4].w;
        }
        *(vf4*)&ob[(size_t)i * DIM] = o0;
        *(vf4*)&ob[(size_t)i * DIM + 256] = o1;
    }
}

extern "C" void kernel_launch(void* const* d_in, const int* in_sizes, int n_in,
                              void* d_out, int out_size, void* d_ws, size_t ws_size,
                              hipStream_t stream) {
    const float* x     = (const float*)d_in[0];
    const float* ctr   = (const float*)d_in[1];
    const float* gamma = (const float*)d_in[2];
    const float* beta  = (const float*)d_in[3];
    const float* W1    = (const float*)d_in[4];
    const float* b1    = (const float*)d_in[5];
    const float* W2    = (const float*)d_in[6];
    const float* b2    = (const float*)d_in[7];
    const float* Wa    = (const float*)d_in[8];
    const float* Wb    = (const float*)d_in[9];

    float* ws = (float*)d_ws;
    float* A  = ws;                  // 131072 floats
    float* B  = ws + 131072;         // 131072 floats
    float* xa = ws + 262144;         // 131072 floats (8*2048*8)
    float* out = (float*)d_out;

    gate_ab_kernel<<<128, 256, 0, stream>>>(ctr, gamma, beta, W1, b1, W2, b2,
                                            Wa, Wb, A, B);
    xa_kernel<<<BS * SEQ / 8, 256, 0, stream>>>(x, A, xa);
    out_kernel<<<BS * SEQ / 16, 256, 0, stream>>>(xa, B, out);
}